// Round 5
// baseline (492.548 us; speedup 1.0000x reference)
//
#include <hip/hip_runtime.h>
#include <math.h>

#define N 4096
#define NFEAT 512
#define HID 128
#define NHEAD 4
#define DH 32
#define NC 16
#define FF 256
#define NSPLIT 32     // k_utx n-split
#define NCHUNK 16     // attention m-chunks
#define CHUNKM (N / NCHUNK)   // 256
#define NGRP (CHUNKM / 128)   // 2 groups of 4 m-tiles

typedef _Float16 f16;
typedef unsigned int uint;
typedef _Float16 f16x8 __attribute__((ext_vector_type(8)));
typedef _Float16 f16x2 __attribute__((ext_vector_type(2)));
typedef float f32x16 __attribute__((ext_vector_type(16)));
typedef uint uint2v __attribute__((ext_vector_type(2)));

#define SCALE 0.17677669529663687f      // 1/sqrt(32)
#define LOG2E 1.44269504088896f
#define SH2   (-14.0f * 1.44269504088896f)   // fixed softmax shift (scores <= ~13.4)

// ---------------------------------------------------------------- K1: feat encoder (8 rows/block)
__global__ __launch_bounds__(256) void k_feat(const float* __restrict__ x,
    const float* __restrict__ w1, const float* __restrict__ b1,
    const float* __restrict__ w2, const float* __restrict__ b2,
    float* __restrict__ h) {
  __shared__ float xs[8][NFEAT];    // 16KB
  __shared__ float h1s[8][HID];     // 4KB
  int r0 = blockIdx.x * 8, tid = threadIdx.x;
  for (int i = tid; i < 8 * (NFEAT / 4); i += 256) {
    int rr = i >> 7, c4 = i & 127;
    ((float4*)xs[rr])[c4] = *(const float4*)(x + (size_t)(r0 + rr) * NFEAT + c4 * 4);
  }
  __syncthreads();
  int c = tid & 127, rb = tid >> 7;
  float acc[4];
#pragma unroll
  for (int i = 0; i < 4; ++i) acc[i] = b1[c];
  for (int k2 = 0; k2 < NFEAT; ++k2) {
    float wv = w1[k2 * HID + c];
#pragma unroll
    for (int i = 0; i < 4; ++i) acc[i] += xs[rb + 2 * i][k2] * wv;
  }
#pragma unroll
  for (int i = 0; i < 4; ++i) h1s[rb + 2 * i][c] = fmaxf(acc[i], 0.f);
  __syncthreads();
  if (tid < 128) {
    int rr = tid >> 4, cc = tid & 15;
    float a2 = b2[cc];
    for (int k2 = 0; k2 < HID; ++k2)
      a2 += h1s[rr][k2] * w2[k2 * NC + cc];
    h[(size_t)(r0 + rr) * NC + cc] = a2;
  }
}

// ---------------------------------------------------------------- K2: sine encoding + eig_w (8 rows/block)
__global__ __launch_bounds__(256) void k_sine_eigw(const float* __restrict__ e,
    const float* __restrict__ eww, const float* __restrict__ ewb,
    f16* __restrict__ sc_h, f16* __restrict__ scS_h, float* __restrict__ eigw) {
  __shared__ float scs[8][HID];
  __shared__ float es[8];
  int r0 = blockIdx.x * 8, tid = threadIdx.x;
  if (tid < 8) es[tid] = e[r0 + tid];
  __syncthreads();
  for (int i = tid; i < 8 * 64; i += 256) {
    int rr = i >> 6, j = i & 63;
    float div = expf((float)(2 * j) * (-0.07195578415606394f)); // -ln(10000)/128
    float pe = es[rr] * 100.0f * div;
    scs[rr][j]      = sinf(pe);
    scs[rr][j + 64] = cosf(pe);
  }
  __syncthreads();
  for (int i = tid; i < 8 * 64; i += 256) {
    int rr = i >> 6, jj = i & 63;
    float x0 = scs[rr][2 * jj], x1 = scs[rr][2 * jj + 1];
    f16x2 a; a[0] = (f16)x0; a[1] = (f16)x1;
    f16x2 b; b[0] = (f16)(x0 * SCALE); b[1] = (f16)(x1 * SCALE);
    ((f16x2*)sc_h)[(size_t)(r0 + rr) * 64 + jj] = a;
    ((f16x2*)scS_h)[(size_t)(r0 + rr) * 64 + jj] = b;
  }
  int c = tid & 127, rb = tid >> 7;
  float acc[4];
#pragma unroll
  for (int i = 0; i < 4; ++i) acc[i] = ewb[c] + es[rb + 2 * i] * eww[c];
  for (int k2 = 0; k2 < HID; ++k2) {
    float wv = eww[(1 + k2) * HID + c];
#pragma unroll
    for (int i = 0; i < 4; ++i) acc[i] += scs[rb + 2 * i][k2] * wv;
  }
#pragma unroll
  for (int i = 0; i < 4; ++i)
    eigw[(size_t)(r0 + rb + 2 * i) * HID + c] = acc[i];
}

// ---------------------------------------------------------------- LayerNorm (1 wave / row)
__global__ __launch_bounds__(256) void k_ln(const float* __restrict__ in,
    const float* __restrict__ g, const float* __restrict__ b, float* __restrict__ out) {
  int row = blockIdx.x * 4 + (threadIdx.x >> 6);
  int l = threadIdx.x & 63;
  float2 v2 = *(const float2*)(in + (size_t)row * HID + l * 2);
  float s = v2.x + v2.y;
  float ss = v2.x * v2.x + v2.y * v2.y;
#pragma unroll
  for (int off = 32; off > 0; off >>= 1) {
    s  += __shfl_down(s, off, 64);
    ss += __shfl_down(ss, off, 64);
  }
  s = __shfl(s, 0, 64); ss = __shfl(ss, 0, 64);
  float mean = s * (1.0f / HID);
  float var = ss * (1.0f / HID) - mean * mean;
  float inv = 1.0f / sqrtf(var + 1e-5f);
  float2 g2 = *(const float2*)(g + l * 2);
  float2 b2 = *(const float2*)(b + l * 2);
  float2 o;
  o.x = (v2.x - mean) * inv * g2.x + b2.x;
  o.y = (v2.y - mean) * inv * g2.y + b2.y;
  *(float2*)(out + (size_t)row * HID + l * 2) = o;
}

// ---------------------------------------------------------------- fused LN1 + Q/K/V projections (8 rows/block)
__global__ __launch_bounds__(256) void k_lnqkv(const float* __restrict__ eigw,
    const float* __restrict__ g, const float* __restrict__ b,
    const float* __restrict__ wq, const float* __restrict__ bq,
    const float* __restrict__ wk, const float* __restrict__ bk,
    const float* __restrict__ wv, const float* __restrict__ bv,
    f16* __restrict__ qh, f16* __restrict__ kh, float* __restrict__ v) {
  __shared__ float as[8][HID];
  int r0 = blockIdx.x * 8, tid = threadIdx.x;
  {
    int rr = tid >> 5, ln = tid & 31;
    float4 x4 = *(const float4*)(eigw + (size_t)(r0 + rr) * HID + ln * 4);
    float s = x4.x + x4.y + x4.z + x4.w;
    float ss = x4.x * x4.x + x4.y * x4.y + x4.z * x4.z + x4.w * x4.w;
#pragma unroll
    for (int off = 16; off > 0; off >>= 1) {
      s  += __shfl_xor(s, off, 32);
      ss += __shfl_xor(ss, off, 32);
    }
    float mean = s * (1.0f / HID);
    float var = ss * (1.0f / HID) - mean * mean;
    float inv = 1.0f / sqrtf(var + 1e-5f);
    float4 g4 = *(const float4*)(g + ln * 4);
    float4 b4 = *(const float4*)(b + ln * 4);
    float4 o;
    o.x = (x4.x - mean) * inv * g4.x + b4.x;
    o.y = (x4.y - mean) * inv * g4.y + b4.y;
    o.z = (x4.z - mean) * inv * g4.z + b4.z;
    o.w = (x4.w - mean) * inv * g4.w + b4.w;
    *(float4*)&as[rr][ln * 4] = o;
  }
  __syncthreads();
  int c = tid & 127, rb = tid >> 7;
  float aq[4], ak[4], av[4];
#pragma unroll
  for (int i = 0; i < 4; ++i) { aq[i] = bq[c]; ak[i] = bk[c]; av[i] = bv[c]; }
  for (int k2 = 0; k2 < HID; ++k2) {
    float wqv = wq[k2 * HID + c];
    float wkv = wk[k2 * HID + c];
    float wvv = wv[k2 * HID + c];
#pragma unroll
    for (int i = 0; i < 4; ++i) {
      float xv = as[rb + 2 * i][k2];
      aq[i] += xv * wqv; ak[i] += xv * wkv; av[i] += xv * wvv;
    }
  }
#pragma unroll
  for (int i = 0; i < 4; ++i) {
    int rr = r0 + rb + 2 * i;
    qh[(size_t)rr * HID + c] = (f16)(aq[i] * SCALE);
    kh[(size_t)rr * HID + c] = (f16)ak[i];
    v[(size_t)rr * HID + c]  = av[i];
  }
}

// ---------------------------------------------------------------- [*,128]@[128,128] (8 rows/block)
template <bool RES, bool F16O>
__global__ __launch_bounds__(256) void k_lin128(const float* __restrict__ in,
    const float* __restrict__ w, const float* __restrict__ bias,
    const float* __restrict__ res, float* __restrict__ out, f16* __restrict__ outh,
    float oscale) {
  __shared__ float as[8][HID];
  int r0 = blockIdx.x * 8, tid = threadIdx.x;
  {
    int rr = tid >> 5, c4 = tid & 31;
    ((float4*)as[rr])[c4] = *(const float4*)(in + (size_t)(r0 + rr) * HID + c4 * 4);
  }
  __syncthreads();
  int c = tid & 127, rb = tid >> 7;
  float acc[4];
#pragma unroll
  for (int i = 0; i < 4; ++i) acc[i] = bias[c];
  for (int k2 = 0; k2 < HID; ++k2) {
    float wv = w[k2 * HID + c];
#pragma unroll
    for (int i = 0; i < 4; ++i) acc[i] += as[rb + 2 * i][k2] * wv;
  }
#pragma unroll
  for (int i = 0; i < 4; ++i) {
    int rr = rb + 2 * i;
    float o = acc[i];
    if (RES) o += res[(size_t)(r0 + rr) * HID + c];
    if (F16O) outh[(size_t)(r0 + rr) * HID + c] = (f16)(o * oscale);
    else      out[(size_t)(r0 + rr) * HID + c] = o;
  }
}

// ---------------------------------------------------------------- v (f32) -> vT (f16, [128][N]); LDS-free
__global__ __launch_bounds__(256) void k_vT(const float* __restrict__ v, f16* __restrict__ vT) {
  int n0 = blockIdx.x * 64, d0 = blockIdx.y * 32, tid = threadIdx.x;
  int d = tid & 31;
#pragma unroll
  for (int it = 0; it < 4; ++it) {
    int j = (tid >> 5) + it * 8;                 // n-pair within 64-row tile
    float x0 = v[(size_t)(n0 + 2 * j) * HID + d0 + d];
    float x1 = v[(size_t)(n0 + 2 * j + 1) * HID + d0 + d];
    f16x2 hh; hh[0] = (f16)x0; hh[1] = (f16)x1;
    ((f16x2*)vT)[((size_t)(d0 + d) * N + n0) / 2 + j] = hh;
  }
}

// ---------------------------------------------------------------- fused MFMA flash attention, rel shared across heads
// 4 waves = 4 heads. Per group of 4 m-tiles: wave w computes rel tile (g*4+w) once (8 mfma),
// exchanges C-fragments via LDS, then every wave does 2 QK + 2 PV mfma per tile.
// NCHUNK=16 + launch_bounds(256,8) -> 8 blocks/CU (latency-bound fix).
__global__ __launch_bounds__(256, 8) void k_attn2(const f16* __restrict__ qh, const f16* __restrict__ kh,
    const f16* __restrict__ vTh, const f16* __restrict__ sch, const f16* __restrict__ scSh,
    float* __restrict__ pacc, float* __restrict__ pl) {
  __shared__ float relbuf[4 * 4 * 64 * 4];   // [tile][reg4-plane][lane][4] = 16KB
  int tid = threadIdx.x, w = tid >> 6, lane = tid & 63, lrow = lane & 31, lhalf = lane >> 5;
  int n0 = blockIdx.x * 32, ntile = blockIdx.x, chunk = blockIdx.y;
  const f16* qp = qh + (size_t)(n0 + lrow) * HID + 32 * w + lhalf * 8;
  f16x8 qb0 = *(const f16x8*)(qp);
  f16x8 qb1 = *(const f16x8*)(qp + 16);
  f32x16 oacc = {0,0,0,0,0,0,0,0,0,0,0,0,0,0,0,0};
  float l = 0.f;
  for (int g = 0; g < NGRP; ++g) {
    // my rel tile: m-tile g*4+w
    int m0my = chunk * CHUNKM + (g * 4 + w) * 32;
    f32x16 rs = {0,0,0,0,0,0,0,0,0,0,0,0,0,0,0,0};
#pragma unroll
    for (int ks = 0; ks < 8; ++ks) {
      f16x8 as = *(const f16x8*)(scSh + (size_t)(m0my + lrow) * HID + ks * 16 + lhalf * 8);
      f16x8 bs = *(const f16x8*)(sch + (size_t)(n0 + lrow) * HID + ks * 16 + lhalf * 8);
      rs = __builtin_amdgcn_mfma_f32_32x32x16_f16(as, bs, rs, 0, 0, 0);
    }
    __syncthreads();   // previous group's reads complete before overwrite
    {
      int base = w * 1024 + lane * 4;
      *(float4*)&relbuf[base +   0] = make_float4(rs[0],  rs[1],  rs[2],  rs[3]);
      *(float4*)&relbuf[base + 256] = make_float4(rs[4],  rs[5],  rs[6],  rs[7]);
      *(float4*)&relbuf[base + 512] = make_float4(rs[8],  rs[9],  rs[10], rs[11]);
      *(float4*)&relbuf[base + 768] = make_float4(rs[12], rs[13], rs[14], rs[15]);
    }
    __syncthreads();
#pragma unroll
    for (int t = 0; t < 4; ++t) {
      int m0 = chunk * CHUNKM + (g * 4 + t) * 32;
      f32x16 sacc;
      {
        int base = t * 1024 + lane * 4;
        float4 r0 = *(const float4*)&relbuf[base +   0];
        float4 r1 = *(const float4*)&relbuf[base + 256];
        float4 r2 = *(const float4*)&relbuf[base + 512];
        float4 r3 = *(const float4*)&relbuf[base + 768];
        sacc[0]=r0.x;  sacc[1]=r0.y;  sacc[2]=r0.z;  sacc[3]=r0.w;
        sacc[4]=r1.x;  sacc[5]=r1.y;  sacc[6]=r1.z;  sacc[7]=r1.w;
        sacc[8]=r2.x;  sacc[9]=r2.y;  sacc[10]=r2.z; sacc[11]=r2.w;
        sacc[12]=r3.x; sacc[13]=r3.y; sacc[14]=r3.z; sacc[15]=r3.w;
      }
      const f16* kp = kh + (size_t)(m0 + lrow) * HID + 32 * w + lhalf * 8;
      f16x8 ka0 = *(const f16x8*)(kp);
      f16x8 ka1 = *(const f16x8*)(kp + 16);
      const f16* vp = vTh + (size_t)(32 * w + lrow) * N + m0 + lhalf * 8;
      f16x8 va0 = *(const f16x8*)(vp);
      f16x8 va1 = *(const f16x8*)(vp + 16);
      sacc = __builtin_amdgcn_mfma_f32_32x32x16_f16(ka0, qb0, sacc, 0, 0, 0);
      sacc = __builtin_amdgcn_mfma_f32_32x32x16_f16(ka1, qb1, sacc, 0, 0, 0);
      // fixed-shift softmax + in-register P->B-frag packing (T12: permlane32_swap)
      uint w0[2], w1[2], w2[2], w3[2];
#pragma unroll
      for (int ks = 0; ks < 2; ++ks) {
        float p[8];
#pragma unroll
        for (int i = 0; i < 8; ++i)
          p[i] = exp2f(fmaf(sacc[ks * 8 + i], LOG2E, SH2));
        l += ((p[0] + p[1]) + (p[2] + p[3])) + ((p[4] + p[5]) + (p[6] + p[7]));
        uint Wa = __builtin_bit_cast(uint, __builtin_amdgcn_cvt_pkrtz(p[0], p[1]));
        uint Wb = __builtin_bit_cast(uint, __builtin_amdgcn_cvt_pkrtz(p[2], p[3]));
        uint Wc = __builtin_bit_cast(uint, __builtin_amdgcn_cvt_pkrtz(p[4], p[5]));
        uint Wd = __builtin_bit_cast(uint, __builtin_amdgcn_cvt_pkrtz(p[6], p[7]));
#if __has_builtin(__builtin_amdgcn_permlane32_swap)
        uint2v r02 = __builtin_amdgcn_permlane32_swap(Wa, Wc, false, false);
        uint2v r13 = __builtin_amdgcn_permlane32_swap(Wb, Wd, false, false);
        w0[ks] = r02[0]; w2[ks] = r02[1];
        w1[ks] = r13[0]; w3[ks] = r13[1];
#else
        uint Wax = (uint)__shfl_xor((int)Wa, 32, 64);
        uint Wbx = (uint)__shfl_xor((int)Wb, 32, 64);
        uint Wcx = (uint)__shfl_xor((int)Wc, 32, 64);
        uint Wdx = (uint)__shfl_xor((int)Wd, 32, 64);
        bool hi = (lhalf != 0);
        w0[ks] = hi ? Wcx : Wa;
        w1[ks] = hi ? Wdx : Wb;
        w2[ks] = hi ? Wc : Wax;
        w3[ks] = hi ? Wd : Wbx;
#endif
      }
      f16x8 pb0 = __builtin_bit_cast(f16x8, make_uint4(w0[0], w1[0], w2[0], w3[0]));
      f16x8 pb1 = __builtin_bit_cast(f16x8, make_uint4(w0[1], w1[1], w2[1], w3[1]));
      oacc = __builtin_amdgcn_mfma_f32_32x32x16_f16(va0, pb0, oacc, 0, 0, 0);
      oacc = __builtin_amdgcn_mfma_f32_32x32x16_f16(va1, pb1, oacc, 0, 0, 0);
    }
  }
  l += __shfl_xor(l, 32, 64);
  float* pp = pacc + ((size_t)(chunk * 4 + w) * 128 + ntile) * 1024 + lane * 16;
  *(float4*)(pp +  0) = make_float4(oacc[0],  oacc[1],  oacc[2],  oacc[3]);
  *(float4*)(pp +  4) = make_float4(oacc[4],  oacc[5],  oacc[6],  oacc[7]);
  *(float4*)(pp +  8) = make_float4(oacc[8],  oacc[9],  oacc[10], oacc[11]);
  *(float4*)(pp + 12) = make_float4(oacc[12], oacc[13], oacc[14], oacc[15]);
  if (lane < 32) pl[(size_t)(chunk * 4 + w) * N + n0 + lrow] = l;
}

// ---------------------------------------------------------------- merge 16 m-chunks (fixed shift -> plain sums)
__global__ __launch_bounds__(256) void k_attn_merge2(const float* __restrict__ pacc,
    const float* __restrict__ pl, float* __restrict__ attno) {
  __shared__ float ao[32][132];
  int tid = threadIdx.x, h = tid >> 6, lane = tid & 63, lrow = lane & 31, lhalf = lane >> 5;
  int ntile = blockIdx.x, n0 = ntile * 32;
  float o[16];
#pragma unroll
  for (int r = 0; r < 16; ++r) o[r] = 0.f;
  float l = 0.f;
#pragma unroll
  for (int c = 0; c < NCHUNK; ++c) {
    const float* pp = pacc + ((size_t)(c * 4 + h) * 128 + ntile) * 1024 + lane * 16;
    float4 r0 = *(const float4*)(pp), r1 = *(const float4*)(pp + 4);
    float4 r2 = *(const float4*)(pp + 8), r3 = *(const float4*)(pp + 12);
    o[0]+=r0.x; o[1]+=r0.y; o[2]+=r0.z; o[3]+=r0.w;
    o[4]+=r1.x; o[5]+=r1.y; o[6]+=r1.z; o[7]+=r1.w;
    o[8]+=r2.x; o[9]+=r2.y; o[10]+=r2.z; o[11]+=r2.w;
    o[12]+=r3.x; o[13]+=r3.y; o[14]+=r3.z; o[15]+=r3.w;
    l += pl[(size_t)(c * 4 + h) * N + n0 + lrow];
  }
  float inv = 1.0f / l;
#pragma unroll
  for (int r = 0; r < 16; ++r) {
    int d = (r & 3) + 8 * (r >> 2) + 4 * lhalf;   // C-layout row
    ao[lrow][h * 32 + d] = o[r] * inv;
  }
  __syncthreads();
  for (int i = tid; i < 32 * 32; i += 256) {
    int row = i >> 5, c4 = i & 31;
    *(float4*)(attno + (size_t)(n0 + row) * HID + c4 * 4) = *(float4*)&ao[row][c4 * 4];
  }
}

// ---------------------------------------------------------------- FFN fused (8 rows/block)
__global__ __launch_bounds__(256) void k_ffn(const float* __restrict__ fln,
    const float* __restrict__ w1, const float* __restrict__ b1,
    const float* __restrict__ w2, const float* __restrict__ b2,
    const float* __restrict__ eig, float* __restrict__ out) {
  __shared__ float fs[8][HID];
  __shared__ float t1[8][FF];
  int r0 = blockIdx.x * 8, tid = threadIdx.x;
  {
    int rr = tid >> 5, c4 = tid & 31;
    ((float4*)fs[rr])[c4] = *(const float4*)(fln + (size_t)(r0 + rr) * HID + c4 * 4);
  }
  __syncthreads();
  {
    float acc[8];
#pragma unroll
    for (int i = 0; i < 8; ++i) acc[i] = b1[tid];
    for (int k2 = 0; k2 < HID; ++k2) {
      float wv = w1[k2 * FF + tid];
#pragma unroll
      for (int i = 0; i < 8; ++i) acc[i] += fs[i][k2] * wv;
    }
#pragma unroll
    for (int i = 0; i < 8; ++i) {
      float xg = acc[i];
      t1[i][tid] = 0.5f * xg * (1.0f + erff(xg * 0.7071067811865476f));
    }
  }
  __syncthreads();
  int c = tid & 127, rb = tid >> 7;
  float acc2[4];
#pragma unroll
  for (int i = 0; i < 4; ++i) acc2[i] = b2[c];
  for (int k2 = 0; k2 < FF; ++k2) {
    float wv = w2[k2 * HID + c];
#pragma unroll
    for (int i = 0; i < 4; ++i) acc2[i] += t1[rb + 2 * i][k2] * wv;
  }
#pragma unroll
  for (int i = 0; i < 4; ++i) {
    int rr = r0 + rb + 2 * i;
    out[(size_t)rr * HID + c] = acc2[i] + eig[(size_t)rr * HID + c];
  }
}

// ---------------------------------------------------------------- decoder (16 rows/block, split-k)
__global__ __launch_bounds__(256) void k_dec(const float* __restrict__ eig2,
    const float* __restrict__ dw, const float* __restrict__ db, float* __restrict__ newe) {
  int tid = threadIdx.x;
  int r = tid >> 4, j = (tid >> 2) & 3, q = tid & 3;
  int n = blockIdx.x * 16 + r;
  const float* ep = eig2 + (size_t)n * HID + q * 32;
  float a = 0.f;
#pragma unroll
  for (int t4 = 0; t4 < 8; ++t4) {
    float4 e4 = *(const float4*)(ep + t4 * 4);
    int k0 = q * 32 + t4 * 4;
    a += e4.x * dw[k0 * NHEAD + j] + e4.y * dw[(k0 + 1) * NHEAD + j]
       + e4.z * dw[(k0 + 2) * NHEAD + j] + e4.w * dw[(k0 + 3) * NHEAD + j];
  }
  a += __shfl_down(a, 1, 64);
  a += __shfl_down(a, 2, 64);
  if (q == 0) newe[n * NHEAD + j] = db[j] + a;
}

// ---------------------------------------------------------------- utx partials: u^T @ h, n-split 32
__global__ __launch_bounds__(256) void k_utx(const float* __restrict__ u,
    const float* __restrict__ h, float* __restrict__ putx) {
  __shared__ float hs[128][NC];   // 8KB
  int tid = threadIdx.x;
  int m = blockIdx.x * 256 + tid;
  int n0 = blockIdx.y * 128;
  for (int i = tid; i < 128 * 4; i += 256) {
    int row = i >> 2, cq = i & 3;
    ((float4*)hs[row])[cq] = *(const float4*)(h + (size_t)(n0 + row) * NC + cq * 4);
  }
  __syncthreads();
  float acc[16];
#pragma unroll
  for (int c = 0; c < 16; ++c) acc[c] = 0.f;
  for (int nb = 0; nb < 16; ++nb) {
    float uv[8];
#pragma unroll
    for (int t = 0; t < 8; ++t)
      uv[t] = u[(size_t)(n0 + nb * 8 + t) * N + m];
#pragma unroll
    for (int t = 0; t < 8; ++t) {
      int nl = nb * 8 + t;
      float4 h0 = ((const float4*)hs[nl])[0];
      float4 h1 = ((const float4*)hs[nl])[1];
      float4 h2 = ((const float4*)hs[nl])[2];
      float4 h3 = ((const float4*)hs[nl])[3];
      acc[0]  += uv[t] * h0.x;  acc[1]  += uv[t] * h0.y;
      acc[2]  += uv[t] * h0.z;  acc[3]  += uv[t] * h0.w;
      acc[4]  += uv[t] * h1.x;  acc[5]  += uv[t] * h1.y;
      acc[6]  += uv[t] * h1.z;  acc[7]  += uv[t] * h1.w;
      acc[8]  += uv[t] * h2.x;  acc[9]  += uv[t] * h2.y;
      acc[10] += uv[t] * h2.z;  acc[11] += uv[t] * h2.w;
      acc[12] += uv[t] * h3.x;  acc[13] += uv[t] * h3.y;
      acc[14] += uv[t] * h3.z;  acc[15] += uv[t] * h3.w;
    }
  }
  float* o = putx + ((size_t)blockIdx.y * N + m) * NC;
  *(float4*)(o +  0) = make_float4(acc[0],  acc[1],  acc[2],  acc[3]);
  *(float4*)(o +  4) = make_float4(acc[4],  acc[5],  acc[6],  acc[7]);
  *(float4*)(o +  8) = make_float4(acc[8],  acc[9],  acc[10], acc[11]);
  *(float4*)(o + 12) = make_float4(acc[12], acc[13], acc[14], acc[15]);
}

// ---------------------------------------------------------------- s build: sum partials, scale, output TRANSPOSED sT[16][N]
__global__ __launch_bounds__(256) void k_sbuild(const float* __restrict__ putx,
    const float* __restrict__ newe, const float* __restrict__ specw,
    float* __restrict__ sT) {
  int i = blockIdx.x * 256 + threadIdx.x;   // (m, cq)
  int m = i >> 2, cq = i & 3;
  float4 t = make_float4(0.f, 0.f, 0.f, 0.f);
#pragma unroll 8
  for (int ch = 0; ch < NSPLIT; ++ch) {
    float4 p = *(const float4*)(putx + ((size_t)ch * N + m) * NC + cq * 4);
    t.x += p.x; t.y += p.y; t.z += p.z; t.w += p.w;
  }
  float4 ne = *(const float4*)(newe + (size_t)m * NHEAD);
  float fac[4];
#pragma unroll
  for (int cc = 0; cc < 4; ++cc) {
    int c = cq * 4 + cc;
    fac[cc] = ne.x * specw[1 * NC + c] + ne.y * specw[2 * NC + c]
            + ne.z * specw[3 * NC + c] + ne.w * specw[4 * NC + c];
  }
  sT[(size_t)(cq * 4 + 0) * N + m] = t.x * fac[0];
  sT[(size_t)(cq * 4 + 1) * N + m] = t.y * fac[1];
  sT[(size_t)(cq * 4 + 2) * N + m] = t.z * fac[2];
  sT[(size_t)(cq * 4 + 3) * N + m] = t.w * fac[3];
}

// ---------------------------------------------------------------- u @ s partials: 16 rows/block, m-split 2
__global__ __launch_bounds__(256) void k_final(const float* __restrict__ u,
    const float* __restrict__ sT, float* __restrict__ pfin) {
  __shared__ float sTl[16][256];   // 16KB
  int tid = threadIdx.x, w = tid >> 6, lane = tid & 63;
  int r0 = blockIdx.x * 16;
  size_t mbase = (size_t)blockIdx.y * 2048;
  float a[4][16];
#pragma unroll
  for (int r = 0; r < 4; ++r)
#pragma unroll
    for (int c = 0; c < 16; ++c) a[r][c] = 0.f;
  for (int chunk = 0; chunk < 8; ++chunk) {
    size_t mc0 = mbase + chunk * 256;
    __syncthreads();
    for (int i = tid; i < 16 * 64; i += 256) {
      int c = i >> 6, q = i & 63;
      ((float4*)&sTl[c][0])[q] = *(const float4*)(sT + (size_t)c * N + mc0 + q * 4);
    }
    __syncthreads();
    float4 u4[4];
#pragma unroll
    for (int r = 0; r < 4; ++r)
      u4[r] = *(const float4*)(u + (size_t)(r0 + w * 4 + r) * N + mc0 + 4 * lane);
#pragma unroll
    for (int c = 0; c < 16; ++c) {
      float4 sv = *(const float4*)&sTl[c][4 * lane];
#pragma unroll
      for (int r = 0; r < 4; ++r)
        a[r][c] += u4[r].x * sv.x + u4[r].y * sv.y + u4[r].z * sv.z + u4[r].w * sv.w;
    }
  }
#pragma unroll
  for (int off = 32; off > 0; off >>= 1)
#pragma unroll
    for (int r = 0; r < 4; ++r)
#pragma unroll
      for (int c = 0; c < 16; ++c)
        a[r][c] += __shfl_xor(a[r][c], off, 64);
  if (lane == 0) {
#pragma unroll
    for (int r = 0; r < 4; ++r) {
      float* op = pfin + ((size_t)blockIdx.y * N + r0 + w * 4 + r) * NC;
      *(float4*)(op +  0) = make_float4(a[r][0],  a[r][1],  a[r][2],  a[r][3]);
      *(float4*)(op +  4) = make_float4(a[r][4],  a[r][5],  a[r][6],  a[r][7]);
      *(float4*)(op +  8) = make_float4(a[r][8],  a[r][9],  a[r][10], a[r][11]);
      *(float4*)(op + 12) = make_float4(a[r][12], a[r][13], a[r][14], a[r][15]);
    }
  }
}

// ---------------------------------------------------------------- final merge: pfin halves + h*specw0
__global__ __launch_bounds__(256) void k_finmerge(const float* __restrict__ pfin,
    const float* __restrict__ h, const float* __restrict__ specw, float* __restrict__ out) {
  int i = blockIdx.x * 256 + threadIdx.x;   // quad id
  int n = i >> 2, cq = i & 3;
  float4 f0 = *(const float4*)(pfin + (size_t)n * NC + cq * 4);
  float4 f1 = *(const float4*)(pfin + ((size_t)N + n) * NC + cq * 4);
  float4 h4 = *(const float4*)(h + (size_t)n * NC + cq * 4);
  int c0 = cq * 4;
  float4 o;
  o.x = f0.x + f1.x + h4.x * specw[c0 + 0];
  o.y = f0.y + f1.y + h4.y * specw[c0 + 1];
  o.z = f0.z + f1.z + h4.z * specw[c0 + 2];
  o.w = f0.w + f1.w + h4.w * specw[c0 + 3];
  *(float4*)(out + (size_t)n * NC + cq * 4) = o;
}

// ================================================================ launcher
extern "C" void kernel_launch(void* const* d_in, const int* in_sizes, int n_in,
                              void* d_out, int out_size, void* d_ws, size_t ws_size,
                              hipStream_t stream) {
  const float* e    = (const float*)d_in[0];
  const float* u    = (const float*)d_in[1];
  const float* x    = (const float*)d_in[2];
  const float* few1 = (const float*)d_in[3];
  const float* feb1 = (const float*)d_in[4];
  const float* few2 = (const float*)d_in[5];
  const float* feb2 = (const float*)d_in[6];
  const float* eww  = (const float*)d_in[7];
  const float* ewb  = (const float*)d_in[8];
  const float* ln1g = (const float*)d_in[9];
  const float* ln1b = (const float*)d_in[10];
  const float* wq   = (const float*)d_in[11];
  const float* bq   = (const float*)d_in[12];
  const float* wk   = (const float*)d_in[13];
  const float* bk   = (const float*)d_in[14];
  const float* wv_  = (const float*)d_in[15];
  const float* bv   = (const float*)d_in[16];
  const float* wo   = (const float*)d_in[17];
  const float* bo   = (const float*)d_in[18];
  const float* ln2g = (const float*)d_in[19];
  const float* ln2b = (const float*)d_in[20];
  const float* fw1  = (const float*)d_in[21];
  const float* fb1  = (const float*)d_in[22];
  const float* fw2  = (const float*)d_in[23];
  const float* fb2  = (const float*)d_in[24];
  const float* dw   = (const float*)d_in[25];
  const float* db   = (const float*)d_in[26];
  const float* spw  = (const float*)d_in[27];
  float* out = (float*)d_out;

  char* wsb = (char*)d_ws;
  auto alloc = [&](size_t bytes) { char* p = wsb; wsb += (bytes + 1023) & ~(size_t)1023; return p; };
  float* h    = (float*)alloc(N * NC * 4);
  f16*  sc_h  = (f16*)alloc(N * HID * 2);
  f16*  scS_h = (f16*)alloc(N * HID * 2);
  float* eigw = (float*)alloc(N * HID * 4);
  f16*  q_h   = (f16*)alloc(N * HID * 2);
  f16*  k_h   = (f16*)alloc(N * HID * 2);
  float* v    = (float*)alloc(N * HID * 4);
  f16*  vT_h  = (f16*)alloc(N * HID * 2);
  float* attno= (float*)alloc(N * HID * 4);
  float* eig  = (float*)alloc(N * HID * 4);
  float* fln  = (float*)alloc(N * HID * 4);
  float* eig2 = (float*)alloc(N * HID * 4);
  float* newe = (float*)alloc(N * NHEAD * 4);
  float* sT   = (float*)alloc((size_t)NC * N * 4);
  float* putx = (float*)alloc((size_t)NSPLIT * N * NC * 4);
  float* pacc = (float*)alloc((size_t)NCHUNK * 4 * 128 * 1024 * 4);
  float* pl   = (float*)alloc((size_t)NCHUNK * 4 * N * 4);
  float* pfin = (float*)alloc((size_t)2 * N * NC * 4);

  k_feat<<<N / 8, 256, 0, stream>>>(x, few1, feb1, few2, feb2, h);
  k_utx<<<dim3(N / 256, NSPLIT), 256, 0, stream>>>(u, h, putx);
  k_sine_eigw<<<N / 8, 256, 0, stream>>>(e, eww, ewb, sc_h, scS_h, eigw);
  k_lnqkv<<<N / 8, 256, 0, stream>>>(eigw, ln1g, ln1b, wq, bq, wk, bk, wv_, bv, q_h, k_h, v);
  k_vT<<<dim3(N / 64, 4), 256, 0, stream>>>(v, vT_h);
  k_attn2<<<dim3(128, NCHUNK), 256, 0, stream>>>(q_h, k_h, vT_h, sc_h, scS_h, pacc, pl);
  k_attn_merge2<<<128, 256, 0, stream>>>(pacc, pl, attno);
  k_lin128<true, false><<<N / 8, 256, 0, stream>>>(attno, wo, bo, eigw, eig, nullptr, 1.0f);
  k_ln<<<N / 4, 256, 0, stream>>>(eig, ln2g, ln2b, fln);
  k_ffn<<<N / 8, 256, 0, stream>>>(fln, fw1, fb1, fw2, fb2, eig, eig2);
  k_dec<<<N / 16, 256, 0, stream>>>(eig2, dw, db, newe);
  k_sbuild<<<N * 4 / 256, 256, 0, stream>>>(putx, newe, spw, sT);
  k_final<<<dim3(N / 16, 2), 256, 0, stream>>>(u, sT, pfin);
  k_finmerge<<<N * 4 / 256, 256, 0, stream>>>(pfin, h, spw, out);
}

// Round 6
// 377.242 us; speedup vs baseline: 1.3057x; 1.3057x over previous
//
#include <hip/hip_runtime.h>
#include <math.h>

#define N 4096
#define NFEAT 512
#define HID 128
#define NHEAD 4
#define DH 32
#define NC 16
#define FF 256
#define NSPLIT 32     // k_utx n-split
#define NCHUNK 16     // attention m-chunks
#define CHUNKM (N / NCHUNK)   // 256
#define NGRP (CHUNKM / 128)   // 2 groups of 4 m-tiles

typedef _Float16 f16;
typedef unsigned int uint;
typedef _Float16 f16x8 __attribute__((ext_vector_type(8)));
typedef _Float16 f16x2 __attribute__((ext_vector_type(2)));
typedef float f32x16 __attribute__((ext_vector_type(16)));
typedef uint uint2v __attribute__((ext_vector_type(2)));

#define SCALE 0.17677669529663687f      // 1/sqrt(32)
#define LOG2E 1.44269504088896f
#define SH2   (-14.0f * 1.44269504088896f)   // fixed softmax shift (scores <= ~13.4)

// ---------------------------------------------------------------- K1: feat encoder (8 rows/block)
__global__ __launch_bounds__(256) void k_feat(const float* __restrict__ x,
    const float* __restrict__ w1, const float* __restrict__ b1,
    const float* __restrict__ w2, const float* __restrict__ b2,
    float* __restrict__ h) {
  __shared__ float xs[8][NFEAT];    // 16KB
  __shared__ float h1s[8][HID];     // 4KB
  int r0 = blockIdx.x * 8, tid = threadIdx.x;
  for (int i = tid; i < 8 * (NFEAT / 4); i += 256) {
    int rr = i >> 7, c4 = i & 127;
    ((float4*)xs[rr])[c4] = *(const float4*)(x + (size_t)(r0 + rr) * NFEAT + c4 * 4);
  }
  __syncthreads();
  int c = tid & 127, rb = tid >> 7;
  float acc[4];
#pragma unroll
  for (int i = 0; i < 4; ++i) acc[i] = b1[c];
  for (int k2 = 0; k2 < NFEAT; ++k2) {
    float wv = w1[k2 * HID + c];
#pragma unroll
    for (int i = 0; i < 4; ++i) acc[i] += xs[rb + 2 * i][k2] * wv;
  }
#pragma unroll
  for (int i = 0; i < 4; ++i) h1s[rb + 2 * i][c] = fmaxf(acc[i], 0.f);
  __syncthreads();
  if (tid < 128) {
    int rr = tid >> 4, cc = tid & 15;
    float a2 = b2[cc];
    for (int k2 = 0; k2 < HID; ++k2)
      a2 += h1s[rr][k2] * w2[k2 * NC + cc];
    h[(size_t)(r0 + rr) * NC + cc] = a2;
  }
}

// ---------------------------------------------------------------- K2: sine encoding + eig_w (8 rows/block)
__global__ __launch_bounds__(256) void k_sine_eigw(const float* __restrict__ e,
    const float* __restrict__ eww, const float* __restrict__ ewb,
    f16* __restrict__ sc_h, f16* __restrict__ scS_h, float* __restrict__ eigw) {
  __shared__ float scs[8][HID];
  __shared__ float es[8];
  int r0 = blockIdx.x * 8, tid = threadIdx.x;
  if (tid < 8) es[tid] = e[r0 + tid];
  __syncthreads();
  for (int i = tid; i < 8 * 64; i += 256) {
    int rr = i >> 6, j = i & 63;
    float div = expf((float)(2 * j) * (-0.07195578415606394f)); // -ln(10000)/128
    float pe = es[rr] * 100.0f * div;
    scs[rr][j]      = sinf(pe);
    scs[rr][j + 64] = cosf(pe);
  }
  __syncthreads();
  for (int i = tid; i < 8 * 64; i += 256) {
    int rr = i >> 6, jj = i & 63;
    float x0 = scs[rr][2 * jj], x1 = scs[rr][2 * jj + 1];
    f16x2 a; a[0] = (f16)x0; a[1] = (f16)x1;
    f16x2 b; b[0] = (f16)(x0 * SCALE); b[1] = (f16)(x1 * SCALE);
    ((f16x2*)sc_h)[(size_t)(r0 + rr) * 64 + jj] = a;
    ((f16x2*)scS_h)[(size_t)(r0 + rr) * 64 + jj] = b;
  }
  int c = tid & 127, rb = tid >> 7;
  float acc[4];
#pragma unroll
  for (int i = 0; i < 4; ++i) acc[i] = ewb[c] + es[rb + 2 * i] * eww[c];
  for (int k2 = 0; k2 < HID; ++k2) {
    float wv = eww[(1 + k2) * HID + c];
#pragma unroll
    for (int i = 0; i < 4; ++i) acc[i] += scs[rb + 2 * i][k2] * wv;
  }
#pragma unroll
  for (int i = 0; i < 4; ++i)
    eigw[(size_t)(r0 + rb + 2 * i) * HID + c] = acc[i];
}

// ---------------------------------------------------------------- LayerNorm (1 wave / row)
__global__ __launch_bounds__(256) void k_ln(const float* __restrict__ in,
    const float* __restrict__ g, const float* __restrict__ b, float* __restrict__ out) {
  int row = blockIdx.x * 4 + (threadIdx.x >> 6);
  int l = threadIdx.x & 63;
  float2 v2 = *(const float2*)(in + (size_t)row * HID + l * 2);
  float s = v2.x + v2.y;
  float ss = v2.x * v2.x + v2.y * v2.y;
#pragma unroll
  for (int off = 32; off > 0; off >>= 1) {
    s  += __shfl_down(s, off, 64);
    ss += __shfl_down(ss, off, 64);
  }
  s = __shfl(s, 0, 64); ss = __shfl(ss, 0, 64);
  float mean = s * (1.0f / HID);
  float var = ss * (1.0f / HID) - mean * mean;
  float inv = 1.0f / sqrtf(var + 1e-5f);
  float2 g2 = *(const float2*)(g + l * 2);
  float2 b2 = *(const float2*)(b + l * 2);
  float2 o;
  o.x = (v2.x - mean) * inv * g2.x + b2.x;
  o.y = (v2.y - mean) * inv * g2.y + b2.y;
  *(float2*)(out + (size_t)row * HID + l * 2) = o;
}

// ---------------------------------------------------------------- fused LN1 + Q/K/V projections (8 rows/block)
__global__ __launch_bounds__(256) void k_lnqkv(const float* __restrict__ eigw,
    const float* __restrict__ g, const float* __restrict__ b,
    const float* __restrict__ wq, const float* __restrict__ bq,
    const float* __restrict__ wk, const float* __restrict__ bk,
    const float* __restrict__ wv, const float* __restrict__ bv,
    f16* __restrict__ qh, f16* __restrict__ kh, float* __restrict__ v) {
  __shared__ float as[8][HID];
  int r0 = blockIdx.x * 8, tid = threadIdx.x;
  {
    int rr = tid >> 5, ln = tid & 31;
    float4 x4 = *(const float4*)(eigw + (size_t)(r0 + rr) * HID + ln * 4);
    float s = x4.x + x4.y + x4.z + x4.w;
    float ss = x4.x * x4.x + x4.y * x4.y + x4.z * x4.z + x4.w * x4.w;
#pragma unroll
    for (int off = 16; off > 0; off >>= 1) {
      s  += __shfl_xor(s, off, 32);
      ss += __shfl_xor(ss, off, 32);
    }
    float mean = s * (1.0f / HID);
    float var = ss * (1.0f / HID) - mean * mean;
    float inv = 1.0f / sqrtf(var + 1e-5f);
    float4 g4 = *(const float4*)(g + ln * 4);
    float4 b4 = *(const float4*)(b + ln * 4);
    float4 o;
    o.x = (x4.x - mean) * inv * g4.x + b4.x;
    o.y = (x4.y - mean) * inv * g4.y + b4.y;
    o.z = (x4.z - mean) * inv * g4.z + b4.z;
    o.w = (x4.w - mean) * inv * g4.w + b4.w;
    *(float4*)&as[rr][ln * 4] = o;
  }
  __syncthreads();
  int c = tid & 127, rb = tid >> 7;
  float aq[4], ak[4], av[4];
#pragma unroll
  for (int i = 0; i < 4; ++i) { aq[i] = bq[c]; ak[i] = bk[c]; av[i] = bv[c]; }
  for (int k2 = 0; k2 < HID; ++k2) {
    float wqv = wq[k2 * HID + c];
    float wkv = wk[k2 * HID + c];
    float wvv = wv[k2 * HID + c];
#pragma unroll
    for (int i = 0; i < 4; ++i) {
      float xv = as[rb + 2 * i][k2];
      aq[i] += xv * wqv; ak[i] += xv * wkv; av[i] += xv * wvv;
    }
  }
#pragma unroll
  for (int i = 0; i < 4; ++i) {
    int rr = r0 + rb + 2 * i;
    qh[(size_t)rr * HID + c] = (f16)(aq[i] * SCALE);
    kh[(size_t)rr * HID + c] = (f16)ak[i];
    v[(size_t)rr * HID + c]  = av[i];
  }
}

// ---------------------------------------------------------------- [*,128]@[128,128] (8 rows/block)
template <bool RES, bool F16O>
__global__ __launch_bounds__(256) void k_lin128(const float* __restrict__ in,
    const float* __restrict__ w, const float* __restrict__ bias,
    const float* __restrict__ res, float* __restrict__ out, f16* __restrict__ outh,
    float oscale) {
  __shared__ float as[8][HID];
  int r0 = blockIdx.x * 8, tid = threadIdx.x;
  {
    int rr = tid >> 5, c4 = tid & 31;
    ((float4*)as[rr])[c4] = *(const float4*)(in + (size_t)(r0 + rr) * HID + c4 * 4);
  }
  __syncthreads();
  int c = tid & 127, rb = tid >> 7;
  float acc[4];
#pragma unroll
  for (int i = 0; i < 4; ++i) acc[i] = bias[c];
  for (int k2 = 0; k2 < HID; ++k2) {
    float wv = w[k2 * HID + c];
#pragma unroll
    for (int i = 0; i < 4; ++i) acc[i] += as[rb + 2 * i][k2] * wv;
  }
#pragma unroll
  for (int i = 0; i < 4; ++i) {
    int rr = rb + 2 * i;
    float o = acc[i];
    if (RES) o += res[(size_t)(r0 + rr) * HID + c];
    if (F16O) outh[(size_t)(r0 + rr) * HID + c] = (f16)(o * oscale);
    else      out[(size_t)(r0 + rr) * HID + c] = o;
  }
}

// ---------------------------------------------------------------- v (f32) -> vT (f16, [128][N]); LDS-free
__global__ __launch_bounds__(256) void k_vT(const float* __restrict__ v, f16* __restrict__ vT) {
  int n0 = blockIdx.x * 64, d0 = blockIdx.y * 32, tid = threadIdx.x;
  int d = tid & 31;
#pragma unroll
  for (int it = 0; it < 4; ++it) {
    int j = (tid >> 5) + it * 8;                 // n-pair within 64-row tile
    float x0 = v[(size_t)(n0 + 2 * j) * HID + d0 + d];
    float x1 = v[(size_t)(n0 + 2 * j + 1) * HID + d0 + d];
    f16x2 hh; hh[0] = (f16)x0; hh[1] = (f16)x1;
    ((f16x2*)vT)[((size_t)(d0 + d) * N + n0) / 2 + j] = hh;
  }
}

// ---------------------------------------------------------------- fused MFMA flash attention, rel shared across heads
// 4 waves = 4 heads. Per group of 4 m-tiles: wave w computes rel tile (g*4+w) once (8 mfma),
// exchanges C-fragments via LDS, then every wave does 2 QK + 2 PV mfma per tile.
// launch_bounds(256,4): compiler lands at ~56 VGPR (<=64) -> HW can run 8 waves/SIMD with
// grid 2048 = 8 blocks/CU. (256,8) forced a 32-VGPR budget -> acc spill to scratch (R5 regression).
__global__ __launch_bounds__(256, 4) void k_attn2(const f16* __restrict__ qh, const f16* __restrict__ kh,
    const f16* __restrict__ vTh, const f16* __restrict__ sch, const f16* __restrict__ scSh,
    float* __restrict__ pacc, float* __restrict__ pl) {
  __shared__ float relbuf[4 * 4 * 64 * 4];   // [tile][reg4-plane][lane][4] = 16KB
  int tid = threadIdx.x, w = tid >> 6, lane = tid & 63, lrow = lane & 31, lhalf = lane >> 5;
  int n0 = blockIdx.x * 32, ntile = blockIdx.x, chunk = blockIdx.y;
  const f16* qp = qh + (size_t)(n0 + lrow) * HID + 32 * w + lhalf * 8;
  f16x8 qb0 = *(const f16x8*)(qp);
  f16x8 qb1 = *(const f16x8*)(qp + 16);
  f32x16 oacc = {0,0,0,0,0,0,0,0,0,0,0,0,0,0,0,0};
  float l = 0.f;
  for (int g = 0; g < NGRP; ++g) {
    // my rel tile: m-tile g*4+w
    int m0my = chunk * CHUNKM + (g * 4 + w) * 32;
    f32x16 rs = {0,0,0,0,0,0,0,0,0,0,0,0,0,0,0,0};
#pragma unroll
    for (int ks = 0; ks < 8; ++ks) {
      f16x8 as = *(const f16x8*)(scSh + (size_t)(m0my + lrow) * HID + ks * 16 + lhalf * 8);
      f16x8 bs = *(const f16x8*)(sch + (size_t)(n0 + lrow) * HID + ks * 16 + lhalf * 8);
      rs = __builtin_amdgcn_mfma_f32_32x32x16_f16(as, bs, rs, 0, 0, 0);
    }
    __syncthreads();   // previous group's reads complete before overwrite
    {
      int base = w * 1024 + lane * 4;
      *(float4*)&relbuf[base +   0] = make_float4(rs[0],  rs[1],  rs[2],  rs[3]);
      *(float4*)&relbuf[base + 256] = make_float4(rs[4],  rs[5],  rs[6],  rs[7]);
      *(float4*)&relbuf[base + 512] = make_float4(rs[8],  rs[9],  rs[10], rs[11]);
      *(float4*)&relbuf[base + 768] = make_float4(rs[12], rs[13], rs[14], rs[15]);
    }
    __syncthreads();
#pragma unroll
    for (int t = 0; t < 4; ++t) {
      int m0 = chunk * CHUNKM + (g * 4 + t) * 32;
      f32x16 sacc;
      {
        int base = t * 1024 + lane * 4;
        float4 r0 = *(const float4*)&relbuf[base +   0];
        float4 r1 = *(const float4*)&relbuf[base + 256];
        float4 r2 = *(const float4*)&relbuf[base + 512];
        float4 r3 = *(const float4*)&relbuf[base + 768];
        sacc[0]=r0.x;  sacc[1]=r0.y;  sacc[2]=r0.z;  sacc[3]=r0.w;
        sacc[4]=r1.x;  sacc[5]=r1.y;  sacc[6]=r1.z;  sacc[7]=r1.w;
        sacc[8]=r2.x;  sacc[9]=r2.y;  sacc[10]=r2.z; sacc[11]=r2.w;
        sacc[12]=r3.x; sacc[13]=r3.y; sacc[14]=r3.z; sacc[15]=r3.w;
      }
      const f16* kp = kh + (size_t)(m0 + lrow) * HID + 32 * w + lhalf * 8;
      f16x8 ka0 = *(const f16x8*)(kp);
      f16x8 ka1 = *(const f16x8*)(kp + 16);
      const f16* vp = vTh + (size_t)(32 * w + lrow) * N + m0 + lhalf * 8;
      f16x8 va0 = *(const f16x8*)(vp);
      f16x8 va1 = *(const f16x8*)(vp + 16);
      sacc = __builtin_amdgcn_mfma_f32_32x32x16_f16(ka0, qb0, sacc, 0, 0, 0);
      sacc = __builtin_amdgcn_mfma_f32_32x32x16_f16(ka1, qb1, sacc, 0, 0, 0);
      // fixed-shift softmax + in-register P->B-frag packing (T12: permlane32_swap)
      uint w0[2], w1[2], w2[2], w3[2];
#pragma unroll
      for (int ks = 0; ks < 2; ++ks) {
        float p[8];
#pragma unroll
        for (int i = 0; i < 8; ++i)
          p[i] = exp2f(fmaf(sacc[ks * 8 + i], LOG2E, SH2));
        l += ((p[0] + p[1]) + (p[2] + p[3])) + ((p[4] + p[5]) + (p[6] + p[7]));
        uint Wa = __builtin_bit_cast(uint, __builtin_amdgcn_cvt_pkrtz(p[0], p[1]));
        uint Wb = __builtin_bit_cast(uint, __builtin_amdgcn_cvt_pkrtz(p[2], p[3]));
        uint Wc = __builtin_bit_cast(uint, __builtin_amdgcn_cvt_pkrtz(p[4], p[5]));
        uint Wd = __builtin_bit_cast(uint, __builtin_amdgcn_cvt_pkrtz(p[6], p[7]));
#if __has_builtin(__builtin_amdgcn_permlane32_swap)
        uint2v r02 = __builtin_amdgcn_permlane32_swap(Wa, Wc, false, false);
        uint2v r13 = __builtin_amdgcn_permlane32_swap(Wb, Wd, false, false);
        w0[ks] = r02[0]; w2[ks] = r02[1];
        w1[ks] = r13[0]; w3[ks] = r13[1];
#else
        uint Wax = (uint)__shfl_xor((int)Wa, 32, 64);
        uint Wbx = (uint)__shfl_xor((int)Wb, 32, 64);
        uint Wcx = (uint)__shfl_xor((int)Wc, 32, 64);
        uint Wdx = (uint)__shfl_xor((int)Wd, 32, 64);
        bool hi = (lhalf != 0);
        w0[ks] = hi ? Wcx : Wa;
        w1[ks] = hi ? Wdx : Wb;
        w2[ks] = hi ? Wc : Wax;
        w3[ks] = hi ? Wd : Wbx;
#endif
      }
      f16x8 pb0 = __builtin_bit_cast(f16x8, make_uint4(w0[0], w1[0], w2[0], w3[0]));
      f16x8 pb1 = __builtin_bit_cast(f16x8, make_uint4(w0[1], w1[1], w2[1], w3[1]));
      oacc = __builtin_amdgcn_mfma_f32_32x32x16_f16(va0, pb0, oacc, 0, 0, 0);
      oacc = __builtin_amdgcn_mfma_f32_32x32x16_f16(va1, pb1, oacc, 0, 0, 0);
    }
  }
  l += __shfl_xor(l, 32, 64);
  float* pp = pacc + ((size_t)(chunk * 4 + w) * 128 + ntile) * 1024 + lane * 16;
  *(float4*)(pp +  0) = make_float4(oacc[0],  oacc[1],  oacc[2],  oacc[3]);
  *(float4*)(pp +  4) = make_float4(oacc[4],  oacc[5],  oacc[6],  oacc[7]);
  *(float4*)(pp +  8) = make_float4(oacc[8],  oacc[9],  oacc[10], oacc[11]);
  *(float4*)(pp + 12) = make_float4(oacc[12], oacc[13], oacc[14], oacc[15]);
  if (lane < 32) pl[(size_t)(chunk * 4 + w) * N + n0 + lrow] = l;
}

// ---------------------------------------------------------------- merge 16 m-chunks (fixed shift -> plain sums)
__global__ __launch_bounds__(256) void k_attn_merge2(const float* __restrict__ pacc,
    const float* __restrict__ pl, float* __restrict__ attno) {
  __shared__ float ao[32][132];
  int tid = threadIdx.x, h = tid >> 6, lane = tid & 63, lrow = lane & 31, lhalf = lane >> 5;
  int ntile = blockIdx.x, n0 = ntile * 32;
  float o[16];
#pragma unroll
  for (int r = 0; r < 16; ++r) o[r] = 0.f;
  float l = 0.f;
#pragma unroll
  for (int c = 0; c < NCHUNK; ++c) {
    const float* pp = pacc + ((size_t)(c * 4 + h) * 128 + ntile) * 1024 + lane * 16;
    float4 r0 = *(const float4*)(pp), r1 = *(const float4*)(pp + 4);
    float4 r2 = *(const float4*)(pp + 8), r3 = *(const float4*)(pp + 12);
    o[0]+=r0.x; o[1]+=r0.y; o[2]+=r0.z; o[3]+=r0.w;
    o[4]+=r1.x; o[5]+=r1.y; o[6]+=r1.z; o[7]+=r1.w;
    o[8]+=r2.x; o[9]+=r2.y; o[10]+=r2.z; o[11]+=r2.w;
    o[12]+=r3.x; o[13]+=r3.y; o[14]+=r3.z; o[15]+=r3.w;
    l += pl[(size_t)(c * 4 + h) * N + n0 + lrow];
  }
  float inv = 1.0f / l;
#pragma unroll
  for (int r = 0; r < 16; ++r) {
    int d = (r & 3) + 8 * (r >> 2) + 4 * lhalf;   // C-layout row
    ao[lrow][h * 32 + d] = o[r] * inv;
  }
  __syncthreads();
  for (int i = tid; i < 32 * 32; i += 256) {
    int row = i >> 5, c4 = i & 31;
    *(float4*)(attno + (size_t)(n0 + row) * HID + c4 * 4) = *(float4*)&ao[row][c4 * 4];
  }
}

// ---------------------------------------------------------------- FFN fused (8 rows/block)
__global__ __launch_bounds__(256) void k_ffn(const float* __restrict__ fln,
    const float* __restrict__ w1, const float* __restrict__ b1,
    const float* __restrict__ w2, const float* __restrict__ b2,
    const float* __restrict__ eig, float* __restrict__ out) {
  __shared__ float fs[8][HID];
  __shared__ float t1[8][FF];
  int r0 = blockIdx.x * 8, tid = threadIdx.x;
  {
    int rr = tid >> 5, c4 = tid & 31;
    ((float4*)fs[rr])[c4] = *(const float4*)(fln + (size_t)(r0 + rr) * HID + c4 * 4);
  }
  __syncthreads();
  {
    float acc[8];
#pragma unroll
    for (int i = 0; i < 8; ++i) acc[i] = b1[tid];
    for (int k2 = 0; k2 < HID; ++k2) {
      float wv = w1[k2 * FF + tid];
#pragma unroll
      for (int i = 0; i < 8; ++i) acc[i] += fs[i][k2] * wv;
    }
#pragma unroll
    for (int i = 0; i < 8; ++i) {
      float xg = acc[i];
      t1[i][tid] = 0.5f * xg * (1.0f + erff(xg * 0.7071067811865476f));
    }
  }
  __syncthreads();
  int c = tid & 127, rb = tid >> 7;
  float acc2[4];
#pragma unroll
  for (int i = 0; i < 4; ++i) acc2[i] = b2[c];
  for (int k2 = 0; k2 < FF; ++k2) {
    float wv = w2[k2 * HID + c];
#pragma unroll
    for (int i = 0; i < 4; ++i) acc2[i] += t1[rb + 2 * i][k2] * wv;
  }
#pragma unroll
  for (int i = 0; i < 4; ++i) {
    int rr = r0 + rb + 2 * i;
    out[(size_t)rr * HID + c] = acc2[i] + eig[(size_t)rr * HID + c];
  }
}

// ---------------------------------------------------------------- decoder (16 rows/block, split-k)
__global__ __launch_bounds__(256) void k_dec(const float* __restrict__ eig2,
    const float* __restrict__ dw, const float* __restrict__ db, float* __restrict__ newe) {
  int tid = threadIdx.x;
  int r = tid >> 4, j = (tid >> 2) & 3, q = tid & 3;
  int n = blockIdx.x * 16 + r;
  const float* ep = eig2 + (size_t)n * HID + q * 32;
  float a = 0.f;
#pragma unroll
  for (int t4 = 0; t4 < 8; ++t4) {
    float4 e4 = *(const float4*)(ep + t4 * 4);
    int k0 = q * 32 + t4 * 4;
    a += e4.x * dw[k0 * NHEAD + j] + e4.y * dw[(k0 + 1) * NHEAD + j]
       + e4.z * dw[(k0 + 2) * NHEAD + j] + e4.w * dw[(k0 + 3) * NHEAD + j];
  }
  a += __shfl_down(a, 1, 64);
  a += __shfl_down(a, 2, 64);
  if (q == 0) newe[n * NHEAD + j] = db[j] + a;
}

// ---------------------------------------------------------------- utx partials: u^T @ h, n-split 32
__global__ __launch_bounds__(256) void k_utx(const float* __restrict__ u,
    const float* __restrict__ h, float* __restrict__ putx) {
  __shared__ float hs[128][NC];   // 8KB
  int tid = threadIdx.x;
  int m = blockIdx.x * 256 + tid;
  int n0 = blockIdx.y * 128;
  for (int i = tid; i < 128 * 4; i += 256) {
    int row = i >> 2, cq = i & 3;
    ((float4*)hs[row])[cq] = *(const float4*)(h + (size_t)(n0 + row) * NC + cq * 4);
  }
  __syncthreads();
  float acc[16];
#pragma unroll
  for (int c = 0; c < 16; ++c) acc[c] = 0.f;
  for (int nb = 0; nb < 16; ++nb) {
    float uv[8];
#pragma unroll
    for (int t = 0; t < 8; ++t)
      uv[t] = u[(size_t)(n0 + nb * 8 + t) * N + m];
#pragma unroll
    for (int t = 0; t < 8; ++t) {
      int nl = nb * 8 + t;
      float4 h0 = ((const float4*)hs[nl])[0];
      float4 h1 = ((const float4*)hs[nl])[1];
      float4 h2 = ((const float4*)hs[nl])[2];
      float4 h3 = ((const float4*)hs[nl])[3];
      acc[0]  += uv[t] * h0.x;  acc[1]  += uv[t] * h0.y;
      acc[2]  += uv[t] * h0.z;  acc[3]  += uv[t] * h0.w;
      acc[4]  += uv[t] * h1.x;  acc[5]  += uv[t] * h1.y;
      acc[6]  += uv[t] * h1.z;  acc[7]  += uv[t] * h1.w;
      acc[8]  += uv[t] * h2.x;  acc[9]  += uv[t] * h2.y;
      acc[10] += uv[t] * h2.z;  acc[11] += uv[t] * h2.w;
      acc[12] += uv[t] * h3.x;  acc[13] += uv[t] * h3.y;
      acc[14] += uv[t] * h3.z;  acc[15] += uv[t] * h3.w;
    }
  }
  float* o = putx + ((size_t)blockIdx.y * N + m) * NC;
  *(float4*)(o +  0) = make_float4(acc[0],  acc[1],  acc[2],  acc[3]);
  *(float4*)(o +  4) = make_float4(acc[4],  acc[5],  acc[6],  acc[7]);
  *(float4*)(o +  8) = make_float4(acc[8],  acc[9],  acc[10], acc[11]);
  *(float4*)(o + 12) = make_float4(acc[12], acc[13], acc[14], acc[15]);
}

// ---------------------------------------------------------------- s build: sum partials, scale, output TRANSPOSED sT[16][N]
__global__ __launch_bounds__(256) void k_sbuild(const float* __restrict__ putx,
    const float* __restrict__ newe, const float* __restrict__ specw,
    float* __restrict__ sT) {
  int i = blockIdx.x * 256 + threadIdx.x;   // (m, cq)
  int m = i >> 2, cq = i & 3;
  float4 t = make_float4(0.f, 0.f, 0.f, 0.f);
#pragma unroll 8
  for (int ch = 0; ch < NSPLIT; ++ch) {
    float4 p = *(const float4*)(putx + ((size_t)ch * N + m) * NC + cq * 4);
    t.x += p.x; t.y += p.y; t.z += p.z; t.w += p.w;
  }
  float4 ne = *(const float4*)(newe + (size_t)m * NHEAD);
  float fac[4];
#pragma unroll
  for (int cc = 0; cc < 4; ++cc) {
    int c = cq * 4 + cc;
    fac[cc] = ne.x * specw[1 * NC + c] + ne.y * specw[2 * NC + c]
            + ne.z * specw[3 * NC + c] + ne.w * specw[4 * NC + c];
  }
  sT[(size_t)(cq * 4 + 0) * N + m] = t.x * fac[0];
  sT[(size_t)(cq * 4 + 1) * N + m] = t.y * fac[1];
  sT[(size_t)(cq * 4 + 2) * N + m] = t.z * fac[2];
  sT[(size_t)(cq * 4 + 3) * N + m] = t.w * fac[3];
}

// ---------------------------------------------------------------- u @ s partials: 16 rows/block, m-split 2
__global__ __launch_bounds__(256) void k_final(const float* __restrict__ u,
    const float* __restrict__ sT, float* __restrict__ pfin) {
  __shared__ float sTl[16][256];   // 16KB
  int tid = threadIdx.x, w = tid >> 6, lane = tid & 63;
  int r0 = blockIdx.x * 16;
  size_t mbase = (size_t)blockIdx.y * 2048;
  float a[4][16];
#pragma unroll
  for (int r = 0; r < 4; ++r)
#pragma unroll
    for (int c = 0; c < 16; ++c) a[r][c] = 0.f;
  for (int chunk = 0; chunk < 8; ++chunk) {
    size_t mc0 = mbase + chunk * 256;
    __syncthreads();
    for (int i = tid; i < 16 * 64; i += 256) {
      int c = i >> 6, q = i & 63;
      ((float4*)&sTl[c][0])[q] = *(const float4*)(sT + (size_t)c * N + mc0 + q * 4);
    }
    __syncthreads();
    float4 u4[4];
#pragma unroll
    for (int r = 0; r < 4; ++r)
      u4[r] = *(const float4*)(u + (size_t)(r0 + w * 4 + r) * N + mc0 + 4 * lane);
#pragma unroll
    for (int c = 0; c < 16; ++c) {
      float4 sv = *(const float4*)&sTl[c][4 * lane];
#pragma unroll
      for (int r = 0; r < 4; ++r)
        a[r][c] += u4[r].x * sv.x + u4[r].y * sv.y + u4[r].z * sv.z + u4[r].w * sv.w;
    }
  }
#pragma unroll
  for (int off = 32; off > 0; off >>= 1)
#pragma unroll
    for (int r = 0; r < 4; ++r)
#pragma unroll
      for (int c = 0; c < 16; ++c)
        a[r][c] += __shfl_xor(a[r][c], off, 64);
  if (lane == 0) {
#pragma unroll
    for (int r = 0; r < 4; ++r) {
      float* op = pfin + ((size_t)blockIdx.y * N + r0 + w * 4 + r) * NC;
      *(float4*)(op +  0) = make_float4(a[r][0],  a[r][1],  a[r][2],  a[r][3]);
      *(float4*)(op +  4) = make_float4(a[r][4],  a[r][5],  a[r][6],  a[r][7]);
      *(float4*)(op +  8) = make_float4(a[r][8],  a[r][9],  a[r][10], a[r][11]);
      *(float4*)(op + 12) = make_float4(a[r][12], a[r][13], a[r][14], a[r][15]);
    }
  }
}

// ---------------------------------------------------------------- final merge: pfin halves + h*specw0
__global__ __launch_bounds__(256) void k_finmerge(const float* __restrict__ pfin,
    const float* __restrict__ h, const float* __restrict__ specw, float* __restrict__ out) {
  int i = blockIdx.x * 256 + threadIdx.x;   // quad id
  int n = i >> 2, cq = i & 3;
  float4 f0 = *(const float4*)(pfin + (size_t)n * NC + cq * 4);
  float4 f1 = *(const float4*)(pfin + ((size_t)N + n) * NC + cq * 4);
  float4 h4 = *(const float4*)(h + (size_t)n * NC + cq * 4);
  int c0 = cq * 4;
  float4 o;
  o.x = f0.x + f1.x + h4.x * specw[c0 + 0];
  o.y = f0.y + f1.y + h4.y * specw[c0 + 1];
  o.z = f0.z + f1.z + h4.z * specw[c0 + 2];
  o.w = f0.w + f1.w + h4.w * specw[c0 + 3];
  *(float4*)(out + (size_t)n * NC + cq * 4) = o;
}

// ================================================================ launcher
extern "C" void kernel_launch(void* const* d_in, const int* in_sizes, int n_in,
                              void* d_out, int out_size, void* d_ws, size_t ws_size,
                              hipStream_t stream) {
  const float* e    = (const float*)d_in[0];
  const float* u    = (const float*)d_in[1];
  const float* x    = (const float*)d_in[2];
  const float* few1 = (const float*)d_in[3];
  const float* feb1 = (const float*)d_in[4];
  const float* few2 = (const float*)d_in[5];
  const float* feb2 = (const float*)d_in[6];
  const float* eww  = (const float*)d_in[7];
  const float* ewb  = (const float*)d_in[8];
  const float* ln1g = (const float*)d_in[9];
  const float* ln1b = (const float*)d_in[10];
  const float* wq   = (const float*)d_in[11];
  const float* bq   = (const float*)d_in[12];
  const float* wk   = (const float*)d_in[13];
  const float* bk   = (const float*)d_in[14];
  const float* wv_  = (const float*)d_in[15];
  const float* bv   = (const float*)d_in[16];
  const float* wo   = (const float*)d_in[17];
  const float* bo   = (const float*)d_in[18];
  const float* ln2g = (const float*)d_in[19];
  const float* ln2b = (const float*)d_in[20];
  const float* fw1  = (const float*)d_in[21];
  const float* fb1  = (const float*)d_in[22];
  const float* fw2  = (const float*)d_in[23];
  const float* fb2  = (const float*)d_in[24];
  const float* dw   = (const float*)d_in[25];
  const float* db   = (const float*)d_in[26];
  const float* spw  = (const float*)d_in[27];
  float* out = (float*)d_out;

  char* wsb = (char*)d_ws;
  auto alloc = [&](size_t bytes) { char* p = wsb; wsb += (bytes + 1023) & ~(size_t)1023; return p; };
  float* h    = (float*)alloc(N * NC * 4);
  f16*  sc_h  = (f16*)alloc(N * HID * 2);
  f16*  scS_h = (f16*)alloc(N * HID * 2);
  float* eigw = (float*)alloc(N * HID * 4);
  f16*  q_h   = (f16*)alloc(N * HID * 2);
  f16*  k_h   = (f16*)alloc(N * HID * 2);
  float* v    = (float*)alloc(N * HID * 4);
  f16*  vT_h  = (f16*)alloc(N * HID * 2);
  float* attno= (float*)alloc(N * HID * 4);
  float* eig  = (float*)alloc(N * HID * 4);
  float* fln  = (float*)alloc(N * HID * 4);
  float* eig2 = (float*)alloc(N * HID * 4);
  float* newe = (float*)alloc(N * NHEAD * 4);
  float* sT   = (float*)alloc((size_t)NC * N * 4);
  float* putx = (float*)alloc((size_t)NSPLIT * N * NC * 4);
  float* pacc = (float*)alloc((size_t)NCHUNK * 4 * 128 * 1024 * 4);
  float* pl   = (float*)alloc((size_t)NCHUNK * 4 * N * 4);
  float* pfin = (float*)alloc((size_t)2 * N * NC * 4);

  k_feat<<<N / 8, 256, 0, stream>>>(x, few1, feb1, few2, feb2, h);
  k_utx<<<dim3(N / 256, NSPLIT), 256, 0, stream>>>(u, h, putx);
  k_sine_eigw<<<N / 8, 256, 0, stream>>>(e, eww, ewb, sc_h, scS_h, eigw);
  k_lnqkv<<<N / 8, 256, 0, stream>>>(eigw, ln1g, ln1b, wq, bq, wk, bk, wv_, bv, q_h, k_h, v);
  k_vT<<<dim3(N / 64, 4), 256, 0, stream>>>(v, vT_h);
  k_attn2<<<dim3(128, NCHUNK), 256, 0, stream>>>(q_h, k_h, vT_h, sc_h, scS_h, pacc, pl);
  k_attn_merge2<<<128, 256, 0, stream>>>(pacc, pl, attno);
  k_lin128<true, false><<<N / 8, 256, 0, stream>>>(attno, wo, bo, eigw, eig, nullptr, 1.0f);
  k_ln<<<N / 4, 256, 0, stream>>>(eig, ln2g, ln2b, fln);
  k_ffn<<<N / 8, 256, 0, stream>>>(fln, fw1, fb1, fw2, fb2, eig, eig2);
  k_dec<<<N / 16, 256, 0, stream>>>(eig2, dw, db, newe);
  k_sbuild<<<N * 4 / 256, 256, 0, stream>>>(putx, newe, spw, sT);
  k_final<<<dim3(N / 16, 2), 256, 0, stream>>>(u, sT, pfin);
  k_finmerge<<<N * 4 / 256, 256, 0, stream>>>(pfin, h, spw, out);
}